// Round 3
// baseline (530.380 us; speedup 1.0000x reference)
//
#include <hip/hip_runtime.h>

// Problem constants (fixed by setup_inputs): B=64, T=1024, V=128, S=256
constexpr int B_ = 64;
constexpr int T_ = 1024;
constexpr int V_ = 128;
constexpr int S_ = 256;
constexpr int CH = 10;            // positions per lane: s = lane*10 + k, covers 640 >= 513
constexpr int RPITCH = 132;       // ring row pitch in floats: 128 cols + 4 zero-pad
constexpr int NRING = 8;          // ring rows (must cover prefetch depth + 2)
constexpr float INV_LN2 = 1.4426950408889634f;
constexpr float LN2 = 0.6931471805599453f;

// One wave (64 lanes) per batch element. Linear-domain scaled forward algorithm:
//   alpha_new[s] = (alpha[s] + alpha[s-1] + skip[s]*alpha[s-2]) * p[t, ext_label[s]]
// Lane-major layout: lane i owns s = 10*i + k. Neighbors s-1, s-2 are registers
// a[k-1], a[k-2] for k>=2; only chunk 0/1 need one cross-lane value (shfl_up of a9).
// Even k  <=> even s <=> blank => p0 broadcast. Odd k => gathered target prob.
// Probabilities come from an LDS ring of exp2'd rows, fed by 5-iteration-deep
// register-prefetched global loads (HBM latency ~900 cyc ~ 5 iters).
__global__ __launch_bounds__(64) void ctc_alpha_lin(
    const float* __restrict__ lp,      // [B,T,V] natural-log softmax
    const int* __restrict__ in_len,    // [B]
    const int* __restrict__ tgt,       // [B,S]
    const int* __restrict__ tgt_len,   // [B]
    float* __restrict__ ws)            // [B] per-batch loss / L
{
    const int b = blockIdx.x;
    const int i = threadIdx.x;        // lane 0..63

    __shared__ float ring[NRING * RPITCH];   // 4224 B; also reused for final dump

    const int L  = tgt_len[b];        // 64..256  => always > 0
    const int Tb = in_len[b];         // 768..1024
    const float* lpb = lp + (size_t)b * T_ * V_;
    const int* tg = tgt + b * S_;

    // zero the pad columns (col 128..131) of every ring row: gathers for invalid
    // odd positions point here and must read exact 0.
    if (i < NRING * 4) ring[(i >> 2) * RPITCH + 128 + (i & 3)] = 0.0f;

    // per-lane odd-chunk metadata: c=0..4 <-> k=2c+1, s=10i+2c+1, label index j=5i+c
    int   labidx[5];
    float skipf[5];
    #pragma unroll
    for (int c = 0; c < 5; ++c) {
        int j = 5 * i + c;
        if (j < L) {
            int lj = tg[j];
            labidx[c] = lj;                                    // gather column
            skipf[c]  = (j >= 1 && lj != tg[j - 1]) ? 1.0f : 0.0f;
        } else {
            labidx[c] = 128;                                   // zero-pad column
            skipf[c]  = 0.0f;
        }
    }

    // init alpha (t=0): a[s=0] = p(0, blank), a[s=1] = p(0, tgt[0]); rest 0
    float a0=0.f,a1=0.f,a2=0.f,a3=0.f,a4=0.f,a5=0.f,a6=0.f,a7=0.f,a8=0.f,a9=0.f;
    {
        float pb = __builtin_exp2f(lpb[0] * INV_LN2);
        float pl = __builtin_exp2f(lpb[tg[0]] * INV_LN2);
        if (i == 0) { a0 = pb; a1 = pl; }
    }

    // prime: rows 1,2 exp'd straight into the ring
    #pragma unroll
    for (int r = 1; r <= 2; ++r) {
        float x0 = lpb[r * V_ + i];
        float x1 = lpb[r * V_ + 64 + i];
        ring[(r & 7) * RPITCH + i]      = __builtin_exp2f(x0 * INV_LN2);
        ring[(r & 7) * RPITCH + 64 + i] = __builtin_exp2f(x1 * INV_LN2);
    }
    // prime: raw rows 3,4,5 in flight in registers
    float ra0 = lpb[3 * V_ + i], ra1 = lpb[3 * V_ + 64 + i];
    float rb0 = lpb[4 * V_ + i], rb1 = lpb[4 * V_ + 64 + i];
    float rc0 = lpb[5 * V_ + i], rc1 = lpb[5 * V_ + 64 + i];
    float rd0 = 0.f, rd1 = 0.f;

    int K = 0;   // accumulated log2 scale: stored_alpha = true_alpha * 2^K

    for (int t = 1; t < Tb; ++t) {
        const int rs_t = (t & 7) * RPITCH;       // slot of exp'd row t

        // issue prefetch of raw row t+5 (consumed as ra at iter t+3, row (t+3)+2)
        if (t + 5 < T_) {
            rd0 = lpb[(t + 5) * V_ + i];
            rd1 = lpb[(t + 5) * V_ + 64 + i];
        }

        // gather probabilities from exp'd row t (LDS reads before LDS writes below,
        // so the compiler's conservative lgkm waits only hit long-retired writes)
        float p0  = ring[rs_t];                  // blank prob, broadcast
        float pg0 = ring[rs_t + labidx[0]];
        float pg1 = ring[rs_t + labidx[1]];
        float pg2 = ring[rs_t + labidx[2]];
        float pg3 = ring[rs_t + labidx[3]];
        float pg4 = ring[rs_t + labidx[4]];

        // cross-lane neighbor: alpha_prev[s-1] for s=10i (and s-2 for s=10i+1)
        float u9 = __shfl_up(a9, 1, 64);
        if (i == 0) u9 = 0.0f;                   // s-1 < 0

        // descending update: chunk k reads a[k], a[k-1], a[k-2] (all still old)
        a9 = (a9 + a8 + skipf[4] * a7) * pg4;
        a8 = (a8 + a7) * p0;
        a7 = (a7 + a6 + skipf[3] * a5) * pg3;
        a6 = (a6 + a5) * p0;
        a5 = (a5 + a4 + skipf[2] * a3) * pg2;
        a4 = (a4 + a3) * p0;
        a3 = (a3 + a2 + skipf[1] * a1) * pg1;
        a2 = (a2 + a1) * p0;
        a1 = (a1 + a0 + skipf[0] * u9) * pg0;
        a0 = (a0 + u9) * p0;

        // stage: exp-transform raw row t+2 into its ring slot (read at iter t+2)
        if (t + 2 < T_) {
            const int rs_w = ((t + 2) & 7) * RPITCH;
            ring[rs_w + i]      = __builtin_exp2f(ra0 * INV_LN2);
            ring[rs_w + 64 + i] = __builtin_exp2f(ra1 * INV_LN2);
        }
        // rotate raw prefetch registers
        ra0 = rb0; ra1 = rb1;
        rb0 = rc0; rb1 = rc1;
        rc0 = rd0; rc1 = rd1;

        // periodic rescale: keep max alpha near 2^124 (wave-uniform scale)
        if ((t & 7) == 0) {
            float m = fmaxf(fmaxf(fmaxf(fmaxf(a0, a1), fmaxf(a2, a3)),
                                  fmaxf(fmaxf(a4, a5), fmaxf(a6, a7))),
                            fmaxf(a8, a9));
            #pragma unroll
            for (int d = 1; d < 64; d <<= 1) m = fmaxf(m, __shfl_xor(m, d, 64));
            int e;
            (void)frexpf(m, &e);                 // m = man * 2^e (e=0 if m==0)
            int ks = 124 - e;
            a0 = ldexpf(a0, ks); a1 = ldexpf(a1, ks);
            a2 = ldexpf(a2, ks); a3 = ldexpf(a3, ks);
            a4 = ldexpf(a4, ks); a5 = ldexpf(a5, ks);
            a6 = ldexpf(a6, ks); a7 = ldexpf(a7, ks);
            a8 = ldexpf(a8, ks); a9 = ldexpf(a9, ks);
            K += ks;
        }
    }

    // dump all positions to LDS (ring reused; 640 <= 1056 floats), read final two
    ring[i * CH + 0] = a0; ring[i * CH + 1] = a1; ring[i * CH + 2] = a2;
    ring[i * CH + 3] = a3; ring[i * CH + 4] = a4; ring[i * CH + 5] = a5;
    ring[i * CH + 6] = a6; ring[i * CH + 7] = a7; ring[i * CH + 8] = a8;
    ring[i * CH + 9] = a9;

    float aB = ring[2 * L];          // uniform address -> broadcast
    float aL = ring[2 * L - 1];      // L >= 64 so 2L-1 >= 0
    if (i == 0) {
        float ll2  = __builtin_log2f(aB + aL);      // -inf if sum==0 (infeasible)
        float ll   = (ll2 - (float)K) * LN2;        // back to natural log
        float loss = -ll;
        if (!(loss <= 1e29f)) loss = 0.0f;          // zero_infinity
        ws[b] = loss / (float)L;
    }
}

__global__ void ctc_reduce_kernel(const float* __restrict__ ws, float* __restrict__ out) {
    float v = ws[threadIdx.x];               // 64 threads, one wave
    #pragma unroll
    for (int o = 32; o > 0; o >>= 1) v += __shfl_down(v, o);
    if (threadIdx.x == 0) out[0] = v / (float)B_;
}

extern "C" void kernel_launch(void* const* d_in, const int* in_sizes, int n_in,
                              void* d_out, int out_size, void* d_ws, size_t ws_size,
                              hipStream_t stream) {
    const float* lp      = (const float*)d_in[0];
    const int*   in_len  = (const int*)d_in[1];
    const int*   tgt     = (const int*)d_in[2];
    const int*   tgt_len = (const int*)d_in[3];
    float* ws  = (float*)d_ws;
    float* out = (float*)d_out;

    ctc_alpha_lin<<<B_, 64, 0, stream>>>(lp, in_len, tgt, tgt_len, ws);
    ctc_reduce_kernel<<<1, 64, 0, stream>>>(ws, out);
}

// Round 4
// 240.487 us; speedup vs baseline: 2.2054x; 2.2054x over previous
//
#include <hip/hip_runtime.h>

// Problem constants (fixed by setup_inputs): B=64, T=1024, V=128, S=256
constexpr int B_ = 64;
constexpr int T_ = 1024;
constexpr int V_ = 128;
constexpr int S_ = 256;
constexpr int PPITCH = 132;       // P row pitch: 128 cols + 4 zero-pad cols
constexpr size_t P_ELEMS = (size_t)B_ * T_ * PPITCH;
constexpr size_t P_BYTES = P_ELEMS * sizeof(float);
constexpr float INV_LN2 = 1.4426950408889634f;
constexpr float LN2 = 0.6931471805599453f;
constexpr float NEGF = -1e30f;

// ---------------- Path A: pre-exp pass + gather-prefetch serial kernel --------

// exp2-transform log-probs into linear probs P[B,T,132]; pad cols = 0.
__global__ __launch_bounds__(256) void exp_rows(const float* __restrict__ lp,
                                                float* __restrict__ P) {
    const int row  = blockIdx.x * 4 + (threadIdx.x >> 6);   // 0 .. B*T-1
    const int lane = threadIdx.x & 63;
    const float* src = lp + (size_t)row * V_ + lane * 2;
    float2 v = *(const float2*)src;
    float2 e;
    e.x = __builtin_exp2f(v.x * INV_LN2);
    e.y = __builtin_exp2f(v.y * INV_LN2);
    float* dst = P + (size_t)row * PPITCH;
    *(float2*)(dst + lane * 2) = e;
    if (lane < 4) dst[V_ + lane] = 0.0f;                    // zero pad cols
}

// One 10-chunk alpha update (linear domain). Chunk k of lane i owns s=10i+k.
__device__ __forceinline__ void step10(
    float& a0, float& a1, float& a2, float& a3, float& a4,
    float& a5, float& a6, float& a7, float& a8, float& a9,
    float p0, float pg0, float pg1, float pg2, float pg3, float pg4,
    const float* skipf, int lane)
{
    float u9 = __shfl_up(a9, 1, 64);     // alpha_prev[s-1] for s=10i
    if (lane == 0) u9 = 0.0f;
    a9 = (a9 + a8 + skipf[4] * a7) * pg4;
    a8 = (a8 + a7) * p0;
    a7 = (a7 + a6 + skipf[3] * a5) * pg3;
    a6 = (a6 + a5) * p0;
    a5 = (a5 + a4 + skipf[2] * a3) * pg2;
    a4 = (a4 + a3) * p0;
    a3 = (a3 + a2 + skipf[1] * a1) * pg1;
    a2 = (a2 + a1) * p0;
    a1 = (a1 + a0 + skipf[0] * u9) * pg0;
    a0 = (a0 + u9) * p0;
}

// One wave per batch element; gathers linear probs straight from global P with
// an 8-iteration-deep rotation-free register pipeline (g[slot] static-indexed
// after full unroll -> no vmcnt(0) drain inside the loop).
__global__ __launch_bounds__(64) void ctc_alpha_gather(
    const float* __restrict__ P,
    const int* __restrict__ in_len,
    const int* __restrict__ tgt,
    const int* __restrict__ tgt_len,
    float* __restrict__ ws)            // [B] per-batch loss / L
{
    const int b = blockIdx.x;
    const int i = threadIdx.x;        // lane 0..63

    __shared__ float fin[640];        // final alpha dump

    const int L  = tgt_len[b];        // 64..256
    const int Tb = in_len[b];         // 768..1024
    const float* Pb = P + (size_t)b * T_ * PPITCH;
    const int* tg = tgt + b * S_;

    // per-lane odd-chunk metadata: c=0..4 <-> s=10i+2c+1, label index j=5i+c
    int   labidx[5];
    float skipf[5];
    #pragma unroll
    for (int c = 0; c < 5; ++c) {
        int j = 5 * i + c;
        if (j < L) {
            int lj = tg[j];
            labidx[c] = lj;
            skipf[c]  = (j >= 1 && lj != tg[j - 1]) ? 1.0f : 0.0f;
        } else {
            labidx[c] = V_;           // zero-pad column -> alpha stays 0
            skipf[c]  = 0.0f;
        }
    }

    // t=0 init
    float a0=0.f,a1=0.f,a2=0.f,a3=0.f,a4=0.f,a5=0.f,a6=0.f,a7=0.f,a8=0.f,a9=0.f;
    {
        float pa = Pb[0];
        float pb2 = Pb[tg[0]];
        if (i == 0) { a0 = pa; a1 = pb2; }
    }

    // prime pipeline: rows 1..8 into slots (row & 7)
    float g[8][6];
    #pragma unroll
    for (int m = 1; m <= 8; ++m) {
        const float* rp = Pb + (size_t)m * PPITCH;
        const int sl = m & 7;
        g[sl][0] = rp[0];
        g[sl][1] = rp[labidx[0]];
        g[sl][2] = rp[labidx[1]];
        g[sl][3] = rp[labidx[2]];
        g[sl][4] = rp[labidx[3]];
        g[sl][5] = rp[labidx[4]];
    }

    int K = 0;     // stored_alpha = true_alpha * 2^K
    int tb = 1;    // tb stays == 1 (mod 8), so slot (tb+p)&7 == (1+p)&7

    for (; tb + 8 <= Tb; tb += 8) {
        #pragma unroll
        for (int p = 0; p < 8; ++p) {
            const int sl = (1 + p) & 7;           // compile-time after unroll
            const int t = tb + p;
            // consume slot sl (row t), then refill with row t+8
            float p0  = g[sl][0];
            float pg0 = g[sl][1];
            float pg1 = g[sl][2];
            float pg2 = g[sl][3];
            float pg3 = g[sl][4];
            float pg4 = g[sl][5];
            const int rnext = (t + 8 < T_) ? (t + 8) : (T_ - 1);
            const float* rp = Pb + (size_t)rnext * PPITCH;
            g[sl][0] = rp[0];
            g[sl][1] = rp[labidx[0]];
            g[sl][2] = rp[labidx[1]];
            g[sl][3] = rp[labidx[2]];
            g[sl][4] = rp[labidx[3]];
            g[sl][5] = rp[labidx[4]];

            step10(a0,a1,a2,a3,a4,a5,a6,a7,a8,a9,
                   p0,pg0,pg1,pg2,pg3,pg4, skipf, i);
        }

        // rescale once per 8 steps: wave-uniform, keep max near 2^124
        float m = fmaxf(fmaxf(fmaxf(fmaxf(a0, a1), fmaxf(a2, a3)),
                              fmaxf(fmaxf(a4, a5), fmaxf(a6, a7))),
                        fmaxf(a8, a9));
        #pragma unroll
        for (int d = 1; d < 64; d <<= 1) m = fmaxf(m, __shfl_xor(m, d, 64));
        int e;
        (void)frexpf(m, &e);
        const int ks = 124 - e;
        a0 = ldexpf(a0, ks); a1 = ldexpf(a1, ks);
        a2 = ldexpf(a2, ks); a3 = ldexpf(a3, ks);
        a4 = ldexpf(a4, ks); a5 = ldexpf(a5, ks);
        a6 = ldexpf(a6, ks); a7 = ldexpf(a7, ks);
        a8 = ldexpf(a8, ks); a9 = ldexpf(a9, ks);
        K += ks;
    }

    // tail: < 8 remaining steps, frozen-select so slot indices stay static
    #pragma unroll
    for (int p = 0; p < 7; ++p) {
        const int sl = (1 + p) & 7;
        const int t = tb + p;
        float c0=a0,c1=a1,c2=a2,c3=a3,c4=a4,c5=a5,c6=a6,c7=a7,c8=a8,c9=a9;
        step10(c0,c1,c2,c3,c4,c5,c6,c7,c8,c9,
               g[sl][0],g[sl][1],g[sl][2],g[sl][3],g[sl][4],g[sl][5],
               skipf, i);
        const bool live = (t < Tb);
        a0 = live ? c0 : a0; a1 = live ? c1 : a1;
        a2 = live ? c2 : a2; a3 = live ? c3 : a3;
        a4 = live ? c4 : a4; a5 = live ? c5 : a5;
        a6 = live ? c6 : a6; a7 = live ? c7 : a7;
        a8 = live ? c8 : a8; a9 = live ? c9 : a9;
    }

    // dump and read the two terminal states
    fin[i * 10 + 0] = a0; fin[i * 10 + 1] = a1; fin[i * 10 + 2] = a2;
    fin[i * 10 + 3] = a3; fin[i * 10 + 4] = a4; fin[i * 10 + 5] = a5;
    fin[i * 10 + 6] = a6; fin[i * 10 + 7] = a7; fin[i * 10 + 8] = a8;
    fin[i * 10 + 9] = a9;
    __syncthreads();

    if (i == 0) {
        float aB = fin[2 * L];
        float aL = fin[2 * L - 1];
        float ll2  = __builtin_log2f(aB + aL);        // -inf if infeasible
        float ll   = (ll2 - (float)K) * LN2;
        float loss = -ll;
        if (!(loss <= 1e29f)) loss = 0.0f;            // zero_infinity
        ws[b] = loss / (float)L;
    }
}

// ---------------- Path B fallback (small ws): proven R2 log-domain kernel -----

constexpr int L2_ = 2 * S_ + 1;
constexpr int NTH = 576;

__device__ __forceinline__ float lae2(float a, float b) {
    float m = fmaxf(a, b);
    return m + __builtin_log2f(__builtin_exp2f(a - m) + __builtin_exp2f(b - m));
}

__global__ __launch_bounds__(NTH) void ctc_alpha_logd(
    const float* __restrict__ lp, const int* __restrict__ in_len,
    const int* __restrict__ tgt, const int* __restrict__ tgt_len,
    float* __restrict__ ws)
{
    const int b = blockIdx.x;
    const int s = threadIdx.x;
    const bool active = s < L2_;
    __shared__ float buf[2][L2_ + 2];
    const int L = tgt_len[b];
    const int Tb = in_len[b];
    int lab = 0; bool skip = false;
    if (active && (s & 1)) {
        int j = s >> 1;
        lab = tgt[b * S_ + j];
        if (s >= 3) skip = (lab != tgt[b * S_ + j - 1]);
    }
    const bool valid = active && (s < 2 * L + 1);
    const float* lpb = lp + (size_t)b * T_ * V_;
    if (s < 2) { buf[0][s] = NEGF; buf[1][s] = NEGF; }
    if (active) {
        float a0 = NEGF;
        if (s == 0) a0 = lpb[0] * INV_LN2;
        else if (s == 1 && L > 0) a0 = lpb[lab] * INV_LN2;
        if (!valid) a0 = NEGF;
        buf[0][2 + s] = a0;
        buf[1][2 + s] = NEGF;
    }
    float lpn = 0.0f;
    if (active) lpn = lpb[V_ + lab];
    const int wlo = s & ~63, whi = wlo + 63;
    int cur = 0;
    for (int t = 1; t < Tb; ++t) {
        const float lpt = lpn * INV_LN2;
        if (active && (t + 1) < Tb) lpn = lpb[(size_t)(t + 1) * V_ + lab];
        __syncthreads();
        bool wave_do = (wlo <= 2 * t + 1) && (whi + 2 * (Tb - 1 - t) >= 2 * L - 1);
        if (wave_do && active) {
            float a0 = buf[cur][2 + s];
            float a1 = buf[cur][1 + s];
            float a2 = skip ? buf[cur][s] : NEGF;
            float m = fmaxf(fmaxf(a0, a1), a2);
            float r = m + __builtin_log2f(__builtin_exp2f(a0 - m) +
                                          __builtin_exp2f(a1 - m) +
                                          __builtin_exp2f(a2 - m));
            buf[cur ^ 1][2 + s] = valid ? (r + lpt) : NEGF;
        }
        cur ^= 1;
    }
    __syncthreads();
    if (s == 0) {
        float ab = buf[cur][2 + 2 * L];
        float al = (L > 0) ? buf[cur][2 + 2 * L - 1] : NEGF;
        float ll = lae2(ab, al) * LN2;
        float loss = -ll;
        if (!(loss <= 1e29f)) loss = 0.0f;
        ws[b] = loss / (float)(L > 0 ? L : 1);
    }
}

// ---------------- reduce ------------------------------------------------------

__global__ void ctc_reduce_kernel(const float* __restrict__ ws, float* __restrict__ out) {
    float v = ws[threadIdx.x];
    #pragma unroll
    for (int o = 32; o > 0; o >>= 1) v += __shfl_down(v, o);
    if (threadIdx.x == 0) out[0] = v / (float)B_;
}

extern "C" void kernel_launch(void* const* d_in, const int* in_sizes, int n_in,
                              void* d_out, int out_size, void* d_ws, size_t ws_size,
                              hipStream_t stream) {
    const float* lp      = (const float*)d_in[0];
    const int*   in_len  = (const int*)d_in[1];
    const int*   tgt     = (const int*)d_in[2];
    const int*   tgt_len = (const int*)d_in[3];
    float* out = (float*)d_out;

    if (ws_size >= P_BYTES + 256) {
        float* P    = (float*)d_ws;
        float* loss = (float*)((char*)d_ws + P_BYTES);
        exp_rows<<<(B_ * T_) / 4, 256, 0, stream>>>(lp, P);
        ctc_alpha_gather<<<B_, 64, 0, stream>>>(P, in_len, tgt, tgt_len, loss);
        ctc_reduce_kernel<<<1, 64, 0, stream>>>(loss, out);
    } else {
        float* loss = (float*)d_ws;
        ctc_alpha_logd<<<B_, NTH, 0, stream>>>(lp, in_len, tgt, tgt_len, loss);
        ctc_reduce_kernel<<<1, 64, 0, stream>>>(loss, out);
    }
}

// Round 5
// 215.945 us; speedup vs baseline: 2.4561x; 1.1136x over previous
//
#include <hip/hip_runtime.h>

// Problem constants (fixed by setup_inputs): B=64, T=1024, V=128, S=256
constexpr int B_ = 64;
constexpr int T_ = 1024;
constexpr int V_ = 128;
constexpr int S_ = 256;
constexpr int RPITCH = 132;                 // ring row pitch: 128 cols + 4 zero pad
constexpr int PAGE_ROWS = 8;
constexpr int NPAGES = 12;                  // ring = 96 rows, 50.7 KB
constexpr int PAGE_F = PAGE_ROWS * RPITCH;  // floats per page (1056)
constexpr float INV_LN2 = 1.4426950408889634f;
constexpr float LN2 = 0.6931471805599453f;

#define WG_SCOPE __HIP_MEMORY_SCOPE_WORKGROUP

// One alpha update (linear domain). Lane i owns s = 10*i + k, k=0..9.
// pg[0] = blank prob; pg[1..5] = gathered label probs for odd k=1,3,5,7,9.
__device__ __forceinline__ void step10(float a[10], const float pg[6],
                                       const float skipf[5], int lane) {
    float u9 = __shfl_up(a[9], 1, 64);      // alpha_prev[s-1] for s = 10*i
    if (lane == 0) u9 = 0.0f;
    a[9] = (a[9] + a[8] + skipf[4] * a[7]) * pg[5];
    a[8] = (a[8] + a[7]) * pg[0];
    a[7] = (a[7] + a[6] + skipf[3] * a[5]) * pg[4];
    a[6] = (a[6] + a[5]) * pg[0];
    a[5] = (a[5] + a[4] + skipf[2] * a[3]) * pg[3];
    a[4] = (a[4] + a[3]) * pg[0];
    a[3] = (a[3] + a[2] + skipf[1] * a[1]) * pg[2];
    a[2] = (a[2] + a[1]) * pg[0];
    a[1] = (a[1] + a[0] + skipf[0] * u9) * pg[1];
    a[0] = (a[0] + u9) * pg[0];
}

__device__ __forceinline__ void rescale(float a[10], int& K) {
    float m = a[0];
    #pragma unroll
    for (int k = 1; k < 10; ++k) m = fmaxf(m, a[k]);
    #pragma unroll
    for (int d = 1; d < 64; d <<= 1) m = fmaxf(m, __shfl_xor(m, d, 64));
    int e;
    (void)frexpf(m, &e);                    // e = 0 if m == 0
    const int ks = 124 - e;
    #pragma unroll
    for (int k = 0; k < 10; ++k) a[k] = ldexpf(a[k], ks);   // v_ldexp_f32
    K += ks;
}

// Consume rows t0+RSTART .. t0+7 of page at sp (spn = next page, used for the
// r=7 prefetch of row t0+8). pg enters holding row t0+RSTART's probs.
// FZ: freeze (select old alpha) for t >= Tb — only the last page needs it.
template<bool FZ, int RSTART>
__device__ __forceinline__ void run_page(
    float a[10], float pg[6], const float* sp, const float* spn,
    const int labE[5], const float skipf[5], int lane, int t0, int Tb)
{
    #pragma unroll
    for (int r = RSTART; r < PAGE_ROWS; ++r) {
        // prefetch probs of row t0+r+1 (immediate row offset; r compile-time)
        const float* bs = (r < 7) ? sp : spn;
        const int ro = (r < 7) ? (r + 1) * RPITCH : 0;
        float nx[6];
        nx[0] = bs[ro];                      // blank col 0 (broadcast)
        #pragma unroll
        for (int c = 0; c < 5; ++c) nx[c + 1] = bs[ro + labE[c]];

        float old[10];
        if (FZ) {
            #pragma unroll
            for (int k = 0; k < 10; ++k) old[k] = a[k];
        }
        step10(a, pg, skipf, lane);
        if (FZ) {
            const bool live = (t0 + r) < Tb;
            #pragma unroll
            for (int k = 0; k < 10; ++k) a[k] = live ? a[k] : old[k];
        }
        #pragma unroll
        for (int c = 0; c < 6; ++c) pg[c] = nx[c];
    }
}

// Fused kernel: one block per batch element. Wave 0 = consumer (serial alpha
// recurrence). Waves 1..4 = producers: stream lp rows, exp2, fill LDS ring.
__global__ __launch_bounds__(320) void ctc_fused(
    const float* __restrict__ lp,      // [B,T,V] natural-log softmax
    const int* __restrict__ in_len,    // [B]
    const int* __restrict__ tgt,       // [B,S]
    const int* __restrict__ tgt_len,   // [B]
    float* __restrict__ ws)            // [B] per-batch loss / L
{
    const int b   = blockIdx.x;
    const int tid = threadIdx.x;
    const int wid = tid >> 6;
    const int lane = tid & 63;

    __shared__ float ring[NPAGES * PAGE_F];   // 12672 floats
    __shared__ int   tags[NPAGES];
    __shared__ int   cons_page;
    __shared__ float fin[640];

    const int L  = tgt_len[b];        // 64..256
    const int Tb = in_len[b];         // 768..1024
    const float* lpb = lp + (size_t)b * T_ * V_;

    // ---- init shared state (tags, ring pad columns) ----
    if (tid < NPAGES) tags[tid] = -1;
    if (tid == NPAGES) cons_page = -1;
    for (int j = tid; j < NPAGES * PAGE_ROWS * 4; j += 320) {
        const int row = j >> 2;
        ring[row * RPITCH + V_ + (j & 3)] = 0.0f;   // pad cols stay 0 forever
    }
    __syncthreads();

    if (wid != 0) {
        // ================= producers =================
        const int q = wid - 1;                       // 0..3; pages q, q+4, ...
        for (int p = q; p * PAGE_ROWS < Tb; p += 4) {
            // ring-full control: slot p%12 free once consumer finished page p-12
            while (__hip_atomic_load(&cons_page, __ATOMIC_RELAXED, WG_SCOPE) < p - NPAGES)
                __builtin_amdgcn_s_sleep(2);

            const int r0 = p * PAGE_ROWS;
            const int n  = min(PAGE_ROWS, Tb - r0);
            float* slot = ring + (p % NPAGES) * PAGE_F;

            float2 v[PAGE_ROWS];
            #pragma unroll
            for (int k = 0; k < PAGE_ROWS; ++k)
                if (k < n) v[k] = *((const float2*)(lpb + (size_t)(r0 + k) * V_) + lane);
            #pragma unroll
            for (int k = 0; k < PAGE_ROWS; ++k)
                if (k < n) {
                    float2 e;
                    e.x = __builtin_exp2f(v[k].x * INV_LN2);
                    e.y = __builtin_exp2f(v[k].y * INV_LN2);
                    *((float2*)(slot + k * RPITCH) + lane) = e;
                }
            // release: all ds_writes drained before tag becomes visible
            __hip_atomic_store(&tags[p % NPAGES], p, __ATOMIC_RELEASE, WG_SCOPE);
        }
        return;
    }

    // ================= consumer (wave 0) =================
    const int* tg = tgt + b * S_;

    // per-lane odd-chunk metadata: c=0..4 <-> s=10*lane+2c+1, label j=5*lane+c
    int   labE[5];
    float skipf[5];
    #pragma unroll
    for (int c = 0; c < 5; ++c) {
        const int j = 5 * lane + c;
        if (j < L) {
            const int lj = tg[j];
            labE[c]  = lj;
            skipf[c] = (j >= 1 && lj != tg[j - 1]) ? 1.0f : 0.0f;
        } else {
            labE[c]  = V_;            // zero-pad column -> alpha stays 0
            skipf[c] = 0.0f;
        }
    }
    const int t0lab = tg[0];

    // wait for page 0, init alpha from row 0
    while (__hip_atomic_load(&tags[0], __ATOMIC_ACQUIRE, WG_SCOPE) != 0)
        __builtin_amdgcn_s_sleep(2);
    float a[10];
    #pragma unroll
    for (int k = 0; k < 10; ++k) a[k] = 0.0f;
    {
        const float r0b = ring[0];
        const float r0l = ring[t0lab];
        if (lane == 0) { a[0] = r0b; a[1] = r0l; }
    }
    // prefetch probs of row 1 (page 0)
    float pg[6];
    pg[0] = ring[RPITCH];
    #pragma unroll
    for (int c = 0; c < 5; ++c) pg[c + 1] = ring[RPITCH + labE[c]];

    int K = 0;                         // stored_alpha = true_alpha * 2^K
    const int pmax = (Tb - 1) / PAGE_ROWS;   // >= 95, so >= NPAGES

    // page 0: rows 1..7 (row 0 was the init); needs page 1 for the r=7 prefetch
    while (__hip_atomic_load(&tags[1], __ATOMIC_ACQUIRE, WG_SCOPE) != 1)
        __builtin_amdgcn_s_sleep(2);
    run_page<false, 1>(a, pg, ring, ring + PAGE_F, labE, skipf, lane, 0, Tb);
    rescale(a, K);
    __hip_atomic_store(&cons_page, 0, __ATOMIC_RELAXED, WG_SCOPE);

    for (int p = 1; p <= pmax; ++p) {
        const int p1 = p + 1;
        if (p1 <= pmax) {
            while (__hip_atomic_load(&tags[p1 % NPAGES], __ATOMIC_ACQUIRE, WG_SCOPE) != p1)
                __builtin_amdgcn_s_sleep(2);
        }
        const float* sp  = ring + (p  % NPAGES) * PAGE_F;
        const float* spn = ring + (p1 % NPAGES) * PAGE_F;  // stale if p1>pmax: unused (frozen)
        if (p < pmax) run_page<false, 0>(a, pg, sp, spn, labE, skipf, lane, 8 * p, Tb);
        else          run_page<true , 0>(a, pg, sp, spn, labE, skipf, lane, 8 * p, Tb);
        rescale(a, K);
        __hip_atomic_store(&cons_page, p, __ATOMIC_RELAXED, WG_SCOPE);
    }

    // dump all positions, read the two terminal states (same-wave LDS ordering
    // is handled by compiler lgkmcnt waits; no barrier needed — producers exited)
    #pragma unroll
    for (int k = 0; k < 10; ++k) fin[lane * 10 + k] = a[k];
    const float aB = fin[2 * L];
    const float aL = fin[2 * L - 1];
    if (lane == 0) {
        const float ll2 = __builtin_log2f(aB + aL);       // -inf if infeasible
        float loss = -((ll2 - (float)K) * LN2);
        if (!(loss <= 1e29f)) loss = 0.0f;                // zero_infinity
        ws[b] = loss / (float)L;
    }
}

__global__ void ctc_reduce_kernel(const float* __restrict__ ws, float* __restrict__ out) {
    float v = ws[threadIdx.x];
    #pragma unroll
    for (int o = 32; o > 0; o >>= 1) v += __shfl_down(v, o);
    if (threadIdx.x == 0) out[0] = v / (float)B_;
}

extern "C" void kernel_launch(void* const* d_in, const int* in_sizes, int n_in,
                              void* d_out, int out_size, void* d_ws, size_t ws_size,
                              hipStream_t stream) {
    const float* lp      = (const float*)d_in[0];
    const int*   in_len  = (const int*)d_in[1];
    const int*   tgt     = (const int*)d_in[2];
    const int*   tgt_len = (const int*)d_in[3];
    float* loss = (float*)d_ws;
    float* out  = (float*)d_out;

    ctc_fused<<<B_, 320, 0, stream>>>(lp, in_len, tgt, tgt_len, loss);
    ctc_reduce_kernel<<<1, 64, 0, stream>>>(loss, out);
}

// Round 8
// 183.982 us; speedup vs baseline: 2.8828x; 1.1737x over previous
//
#include <hip/hip_runtime.h>

// Problem constants (fixed by setup_inputs): B=64, T=1024, V=128, S=256
constexpr int B_ = 64;
constexpr int T_ = 1024;
constexpr int V_ = 128;
constexpr int S_ = 256;
constexpr int GRING = 16;            // staged rows per direction (4 blocks of 4)
constexpr int ROWF = 384;            // floats per staged row: 3 planes x 64 lanes x float2
constexpr int NGW = 5;               // gather waves per direction
constexpr float INV_LN2 = 1.4426950408889634f;
constexpr float LN2 = 0.6931471805599453f;

#define WG_SCOPE __HIP_MEMORY_SCOPE_WORKGROUP

__device__ __forceinline__ void poll_eq(int* p, int want) {
    while (__hip_atomic_load(p, __ATOMIC_ACQUIRE, WG_SCOPE) != want)
        __builtin_amdgcn_s_sleep(2);
}

// Wave-uniform rescale: butterfly max over 64 lanes, shift wave max to ~2^123.
// Returns ks so callers can re-frame in-flight cross-lane registers.
__device__ __forceinline__ int wave_rescale(float a[10], int& K) {
    float mx = a[0];
    #pragma unroll
    for (int k = 1; k < 10; ++k) mx = fmaxf(mx, a[k]);
    #pragma unroll
    for (int d = 1; d < 64; d <<= 1) mx = fmaxf(mx, __shfl_xor(mx, d, 64));
    int e;
    (void)frexpf(mx, &e);
    const int ks = (mx > 0.0f) ? (124 - e) : 0;
    #pragma unroll
    for (int k = 0; k < 10; ++k) a[k] = ldexpf(a[k], ks);
    K += ks;
    return ks;
}

// Fused: 1 block / batch element. wave0 = forward alpha, wave1 = backward beta,
// waves 2..6 = fwd gatherers, 7..11 = bwd gatherers. Linear domain, wave-uniform K.
__global__ __launch_bounds__(768) void ctc_fused4(
    const float* __restrict__ lp,      // [B,T,V] natural-log softmax
    const int* __restrict__ in_len,    // [B]
    const int* __restrict__ tgt,       // [B,S]
    const int* __restrict__ tgt_len,   // [B]
    float* __restrict__ ws)            // [B] per-batch loss / L
{
    const int b    = blockIdx.x;
    const int tid  = threadIdx.x;
    const int wid  = tid >> 6;
    const int lane = tid & 63;

    __shared__ float ringF[GRING * ROWF];    // 24 KB
    __shared__ float ringB[GRING * ROWF];    // 24 KB
    __shared__ float dumpA[640];
    __shared__ float dumpB[640];
    __shared__ int   tagF[4], tagB[4];
    __shared__ int   consF, consB;
    __shared__ int   KFsh, KBsh;

    const int L  = tgt_len[b];        // 64..256
    const int Tb = in_len[b];         // 768..1024
    const float* lpb = lp + (size_t)b * T_ * V_;
    const int* tg = tgt + b * S_;

    const int tm = (Tb - 2) >> 1;
    const int Uf = tm;                // fwd steps: u=1..Uf, row t=u -> alpha_tm
    const int Ub = Tb - 2 - tm;       // bwd steps: u=1..Ub, row t=Tb-1-u -> g_{tm+1}

    if (tid == 0) { consF = 0; consB = 0; }
    if (tid < 4) tagF[tid] = -1;
    else if (tid < 8) tagB[tid - 4] = -1;
    __syncthreads();

    if (wid >= 2) {
        // ======================= gatherers =======================
        const int dir = (wid - 2) / NGW;           // 0 = fwd, 1 = bwd
        const int q   = (wid - 2) % NGW;
        const int U   = dir ? Ub : Uf;
        float* ring   = dir ? ringB : ringF;
        int*   tags   = dir ? tagB  : tagF;
        int*   consp  = dir ? &consB : &consF;

        int   labE[5];
        float vmask[5];
        #pragma unroll
        for (int c = 0; c < 5; ++c) {
            const int j = 5 * lane + c;
            if (j < L) { labE[c] = tg[j]; vmask[c] = 1.0f; }
            else       { labE[c] = 0;     vmask[c] = 0.0f; }
        }

        for (int m = q; 4 * m + 1 <= U; m += NGW) {
            const int n = min(4, U - 4 * m);       // rows u = 4m+1 .. 4m+n
            float v[4][6];
            #pragma unroll
            for (int r = 0; r < 4; ++r) {
                if (r < n) {
                    const int u = 4 * m + 1 + r;
                    const int t = dir ? (Tb - 1 - u) : u;
                    const float* row = lpb + (size_t)t * V_;
                    v[r][0] = row[0];
                    #pragma unroll
                    for (int c = 0; c < 5; ++c) v[r][c + 1] = row[labE[c]];
                }
            }
            // ring-slot reuse gate: block m-4's rows consumed
            while (__hip_atomic_load(consp, __ATOMIC_RELAXED, WG_SCOPE) < 4 * m - 12)
                __builtin_amdgcn_s_sleep(2);
            #pragma unroll
            for (int r = 0; r < 4; ++r) {
                if (r < n) {
                    const int u = 4 * m + 1 + r;
                    float e[6];
                    e[0] = __builtin_exp2f(v[r][0] * INV_LN2);
                    #pragma unroll
                    for (int c = 0; c < 5; ++c)
                        e[c + 1] = vmask[c] * __builtin_exp2f(v[r][c + 1] * INV_LN2);
                    float* rb = ring + (u & (GRING - 1)) * ROWF;
                    ((float2*)rb)[lane]         = make_float2(e[0], e[1]);
                    ((float2*)(rb + 128))[lane] = make_float2(e[2], e[3]);
                    ((float2*)(rb + 256))[lane] = make_float2(e[4], e[5]);
                }
            }
            if (lane == 0)
                __hip_atomic_store(&tags[m & 3], m, __ATOMIC_RELEASE, WG_SCOPE);
        }
    } else if (wid == 0) {
        // ======================= forward consumer =======================
        float skipf[5];
        #pragma unroll
        for (int c = 0; c < 5; ++c) {
            const int j = 5 * lane + c;
            skipf[c] = (j >= 1 && j < L && tg[j] != tg[j - 1]) ? 1.0f : 0.0f;
        }
        float a[10];
        #pragma unroll
        for (int k = 0; k < 10; ++k) a[k] = 0.0f;
        {
            const float p00 = __builtin_exp2f(lpb[0] * INV_LN2);
            const float p01 = __builtin_exp2f(lpb[tg[0]] * INV_LN2);
            if (lane == 0) { a[0] = p00; a[1] = p01; }
        }
        poll_eq(&tagF[0], 0);
        int polled = 0, K = 0;
        const float2* rg = (const float2*)ringF;   // slot r base = r*192 (float2 units)
        float2 A0, A1, A2, B0, B1, B2;             // rows u (odd) / u+1 (even), 2-deep
        { const float2* rp = rg + 1 * 192; A0 = rp[lane]; A1 = rp[64 + lane]; A2 = rp[128 + lane]; }
        { const float2* rp = rg + 2 * 192; B0 = rp[lane]; B1 = rp[64 + lane]; B2 = rp[128 + lane]; }
        float u9n = 0.0f;                          // alpha_prev[s-1] inflow for next row

        auto rowF = [&](float2& c0, float2& c1, float2& c2, int uu) {
            if (uu + 2 <= Uf) {                    // tag for block of row uu+2
                const int mp = (uu + 1) >> 2;
                if (mp > polled) { poll_eq(&tagF[mp & 3], mp); polled = mp; }
            }
            const float u9 = u9n;
            const float p0 = c0.x;
            a[9] = (a[9] + a[8] + skipf[4] * a[7]) * c2.y;
            const float t9 = __shfl_up(a[9], 1, 64);   // early-produce for next row
            u9n = (lane == 0) ? 0.0f : t9;
            a[8] = (a[8] + a[7]) * p0;
            a[7] = (a[7] + a[6] + skipf[3] * a[5]) * c2.x;
            a[6] = (a[6] + a[5]) * p0;
            a[5] = (a[5] + a[4] + skipf[2] * a[3]) * c1.y;
            a[4] = (a[4] + a[3]) * p0;
            a[3] = (a[3] + a[2] + skipf[1] * a[1]) * c1.x;
            a[2] = (a[2] + a[1]) * p0;
            a[1] = (a[1] + a[0] + skipf[0] * u9) * c0.y;   // late-consume u9
            a[0] = (a[0] + u9) * p0;
            if (uu + 2 <= Uf) {                    // refill this parity slot (dist 2)
                const float2* rp = rg + ((uu + 2) & 15) * 192;
                c0 = rp[lane]; c1 = rp[64 + lane]; c2 = rp[128 + lane];
            }
        };

        int u = 1;
        for (; u + 1 <= Uf; u += 2) {
            rowF(A0, A1, A2, u);
            rowF(B0, B1, B2, u + 1);
            if (((u + 1) & 7) == 0) {
                const int ks = wave_rescale(a, K);
                u9n = ldexpf(u9n, ks);             // re-frame in-flight inflow
                if (lane == 0) __hip_atomic_store(&consF, u + 1, __ATOMIC_RELAXED, WG_SCOPE);
            }
        }
        if (u <= Uf) rowF(A0, A1, A2, u);

        #pragma unroll
        for (int k = 0; k < 10; ++k) dumpA[10 * lane + k] = a[k];   // native scale
        if (lane == 0) {
            KFsh = K;
            __hip_atomic_store(&consF, Uf + 64, __ATOMIC_RELAXED, WG_SCOPE);
        }
    } else {
        // ======================= backward consumer =======================
        float sB[5];                  // skip into s+2 (odd): label j = 5*lane+c+1
        #pragma unroll
        for (int c = 0; c < 5; ++c) {
            const int j = 5 * lane + c + 1;
            sB[c] = (j < L && tg[j] != tg[j - 1]) ? 1.0f : 0.0f;
        }
        float g[10];
        #pragma unroll
        for (int k = 0; k < 10; ++k) g[k] = 0.0f;
        {   // g_{Tb-1}: nonzero at s=2L (blank) and s=2L-1 (last label)
            const float pb = __builtin_exp2f(lpb[(size_t)(Tb - 1) * V_] * INV_LN2);
            const float pl = __builtin_exp2f(lpb[(size_t)(Tb - 1) * V_ + tg[L - 1]] * INV_LN2);
            #pragma unroll
            for (int k = 0; k < 10; ++k) {
                const int s = 10 * lane + k;
                if (s == 2 * L)     g[k] = pb;
                if (s == 2 * L - 1) g[k] = pl;
            }
        }
        float t0 = __shfl_down(g[0], 1, 64), t1 = __shfl_down(g[1], 1, 64);
        float d0n = (lane == 63) ? 0.0f : t0;
        float d1n = (lane == 63) ? 0.0f : t1;
        poll_eq(&tagB[0], 0);
        int polled = 0, K = 0;
        const float2* rg = (const float2*)ringB;
        float2 A0, A1, A2, B0, B1, B2;
        { const float2* rp = rg + 1 * 192; A0 = rp[lane]; A1 = rp[64 + lane]; A2 = rp[128 + lane]; }
        { const float2* rp = rg + 2 * 192; B0 = rp[lane]; B1 = rp[64 + lane]; B2 = rp[128 + lane]; }

        auto rowB = [&](float2& c0, float2& c1, float2& c2, int uu) {
            if (uu + 2 <= Ub) {
                const int mp = (uu + 1) >> 2;
                if (mp > polled) { poll_eq(&tagB[mp & 3], mp); polled = mp; }
            }
            const float d0 = d0n, d1 = d1n;
            const float p0 = c0.x;
            g[0] = (g[0] + g[1]) * p0;
            g[1] = (g[1] + g[2] + sB[0] * g[3]) * c0.y;
            const float q0 = __shfl_down(g[0], 1, 64);   // early-produce
            const float q1 = __shfl_down(g[1], 1, 64);
            d0n = (lane == 63) ? 0.0f : q0;
            d1n = (lane == 63) ? 0.0f : q1;
            g[2] = (g[2] + g[3]) * p0;
            g[3] = (g[3] + g[4] + sB[1] * g[5]) * c1.x;
            g[4] = (g[4] + g[5]) * p0;
            g[5] = (g[5] + g[6] + sB[2] * g[7]) * c1.y;
            g[6] = (g[6] + g[7]) * p0;
            g[7] = (g[7] + g[8] + sB[3] * g[9]) * c2.x;
            g[8] = (g[8] + g[9]) * p0;
            g[9] = (g[9] + d0 + sB[4] * d1) * c2.y;      // late-consume
            if (uu + 2 <= Ub) {
                const float2* rp = rg + ((uu + 2) & 15) * 192;
                c0 = rp[lane]; c1 = rp[64 + lane]; c2 = rp[128 + lane];
            }
        };

        int u = 1;
        for (; u + 1 <= Ub; u += 2) {
            rowB(A0, A1, A2, u);
            rowB(B0, B1, B2, u + 1);
            if (((u + 1) & 7) == 0) {
                const int ks = wave_rescale(g, K);
                d0n = ldexpf(d0n, ks);
                d1n = ldexpf(d1n, ks);
                if (lane == 0) __hip_atomic_store(&consB, u + 1, __ATOMIC_RELAXED, WG_SCOPE);
            }
        }
        if (u <= Ub) rowB(A0, A1, A2, u);

        {   // combine: gext[s] = g[s] + g[s+1] + skip[s+2]*g[s+2] (ascending, in place)
            const float d0 = d0n, d1 = d1n;
            g[0] = g[0] + g[1];
            g[1] = g[1] + g[2] + sB[0] * g[3];
            g[2] = g[2] + g[3];
            g[3] = g[3] + g[4] + sB[1] * g[5];
            g[4] = g[4] + g[5];
            g[5] = g[5] + g[6] + sB[2] * g[7];
            g[6] = g[6] + g[7];
            g[7] = g[7] + g[8] + sB[3] * g[9];
            g[8] = g[8] + g[9];
            g[9] = g[9] + d0 + sB[4] * d1;
        }
        #pragma unroll
        for (int k = 0; k < 10; ++k) dumpB[10 * lane + k] = g[k];   // native scale
        if (lane == 0) {
            KBsh = K;
            __hip_atomic_store(&consB, Ub + 64, __ATOMIC_RELAXED, WG_SCOPE);
        }
    }

    __syncthreads();
    if (wid == 0) {
        // join in DOUBLE: factors span ~240 bits in f32 frames; the product's
        // dominant term sits ~2^-230 below maxA*maxB — f32 flushes it (R7 bug).
        double sum = 0.0;
        #pragma unroll
        for (int k = 0; k < 10; ++k)
            sum += (double)dumpA[10 * lane + k] * (double)dumpB[10 * lane + k];
        #pragma unroll
        for (int d = 1; d < 64; d <<= 1) sum += __shfl_xor(sum, d, 64);
        if (lane == 0) {
            float loss = 0.0f;                     // default for infeasible (sum<=0)
            if (sum > 0.0) {
                const long long ub = __double_as_longlong(sum);
                const int ex = (int)((ub >> 52) & 2047) - 1023;       // sum = f*2^ex
                const double f = __longlong_as_double(
                    (ub & 0x000FFFFFFFFFFFFFLL) | 0x3FF0000000000000LL);  // f in [1,2)
                const float ll2 = __builtin_log2f((float)f)
                                + (float)(ex - KFsh - KBsh);
                loss = -(ll2 * LN2);
                if (!(loss <= 1e29f)) loss = 0.0f; // zero_infinity
            }
            ws[b] = loss / (float)L;
        }
    }
}

__global__ void ctc_reduce_kernel(const float* __restrict__ ws, float* __restrict__ out) {
    float v = ws[threadIdx.x];
    #pragma unroll
    for (int o = 32; o > 0; o >>= 1) v += __shfl_down(v, o);
    if (threadIdx.x == 0) out[0] = v / (float)B_;
}

extern "C" void kernel_launch(void* const* d_in, const int* in_sizes, int n_in,
                              void* d_out, int out_size, void* d_ws, size_t ws_size,
                              hipStream_t stream) {
    const float* lp      = (const float*)d_in[0];
    const int*   in_len  = (const int*)d_in[1];
    const int*   tgt     = (const int*)d_in[2];
    const int*   tgt_len = (const int*)d_in[3];
    float* loss = (float*)d_ws;
    float* out  = (float*)d_out;

    ctc_fused4<<<B_, 768, 0, stream>>>(lp, in_len, tgt, tgt_len, loss);
    ctc_reduce_kernel<<<1, 64, 0, stream>>>(loss, out);
}

// Round 10
// 137.112 us; speedup vs baseline: 3.8682x; 1.3418x over previous
//
#include <hip/hip_runtime.h>

// Problem constants (fixed by setup_inputs): B=64, T=1024, V=128, S=256
constexpr int B_ = 64;
constexpr int T_ = 1024;
constexpr int V_ = 128;
constexpr int S_ = 256;
constexpr int GRING = 32;            // staged rows per direction (8 blocks of 4)
constexpr int ROWF = 384;            // floats per staged row: 3 planes x 64 lanes x float2
constexpr int NGW = 5;               // gather waves per direction
constexpr float INV_LN2 = 1.4426950408889634f;
constexpr float LN2 = 0.6931471805599453f;

#define WG_SCOPE __HIP_MEMORY_SCOPE_WORKGROUP

__device__ __forceinline__ void poll_eq(int* p, int want) {
    // RELAXED: LDS is physically shared per-CU; producer's RELEASE store
    // already drained its ds_writes before the tag became visible.
    // (ACQUIRE here would insert lgkmcnt(0) and drain our prefetch queue.)
    while (__hip_atomic_load(p, __ATOMIC_RELAXED, WG_SCOPE) != want)
        __builtin_amdgcn_s_sleep(1);
}

// Wave-uniform butterfly rescale: pin wave max to 2^124 (R8-proven: with
// worst realistic decay ~12.6 bits/row, floor after 8 rows stays > 2^20).
// R9 LESSON: 16-row period with fixed mid-boost flushes to denormal->0.
__device__ __forceinline__ int wave_rescale(float a[10], int& K) {
    float mx = a[0];
    #pragma unroll
    for (int k = 1; k < 10; ++k) mx = fmaxf(mx, a[k]);
    #pragma unroll
    for (int d = 1; d < 64; d <<= 1) mx = fmaxf(mx, __shfl_xor(mx, d, 64));
    int e;
    (void)frexpf(mx, &e);
    const int ks = (mx > 0.0f) ? (124 - e) : 0;
    #pragma unroll
    for (int k = 0; k < 10; ++k) a[k] = ldexpf(a[k], ks);
    K += ks;
    return ks;
}

// Fused: 1 block / batch element. wave0 = forward alpha, wave1 = backward beta,
// waves 2..6 = fwd gatherers, 7..11 = bwd gatherers. Linear domain, wave-uniform K.
__global__ __launch_bounds__(768) void ctc_fused6(
    const float* __restrict__ lp,      // [B,T,V] natural-log softmax
    const int* __restrict__ in_len,    // [B]
    const int* __restrict__ tgt,       // [B,S]
    const int* __restrict__ tgt_len,   // [B]
    float* __restrict__ ws)            // [B] per-batch loss / L
{
    const int b    = blockIdx.x;
    const int tid  = threadIdx.x;
    const int wid  = tid >> 6;
    const int lane = tid & 63;

    __shared__ float ringF[GRING * ROWF];    // 48 KB
    __shared__ float ringB[GRING * ROWF];    // 48 KB
    __shared__ float dumpA[640];
    __shared__ float dumpB[640];
    __shared__ int   tagF[8], tagB[8];
    __shared__ int   consF, consB;
    __shared__ int   KFsh, KBsh;

    const int L  = tgt_len[b];        // 64..256
    const int Tb = in_len[b];         // 768..1024
    const float* lpb = lp + (size_t)b * T_ * V_;
    const int* tg = tgt + b * S_;

    const int tm = (Tb - 2) >> 1;
    const int Uf = tm;                // fwd steps: u=1..Uf (row t=u) -> alpha_tm
    const int Ub = Tb - 2 - tm;       // bwd steps: u=1..Ub (row t=Tb-1-u) -> g_{tm+1}

    if (tid == 0) { consF = 0; consB = 0; }
    if (tid < 8) tagF[tid] = -1;
    else if (tid < 16) tagB[tid - 8] = -1;
    __syncthreads();

    if (wid >= 2) {
        // ======================= gatherers =======================
        const int dir = (wid - 2) / NGW;           // 0 = fwd, 1 = bwd
        const int q   = (wid - 2) % NGW;
        const int U   = dir ? Ub : Uf;
        float* ring   = dir ? ringB : ringF;
        int*   tags   = dir ? tagB  : tagF;
        int*   consp  = dir ? &consB : &consF;

        int   labE[5];
        float vmask[5];
        #pragma unroll
        for (int c = 0; c < 5; ++c) {
            const int j = 5 * lane + c;
            if (j < L) { labE[c] = tg[j]; vmask[c] = 1.0f; }
            else       { labE[c] = 0;     vmask[c] = 0.0f; }
        }

        // block m covers rows u = 4m+1 .. 4m+4; row u lives at slot (u-1)&31
        for (int m = q; 4 * m + 1 <= U; m += NGW) {
            const int n = min(4, U - 4 * m);
            float v[4][6];
            #pragma unroll
            for (int r = 0; r < 4; ++r) {
                if (r < n) {
                    const int u = 4 * m + 1 + r;
                    const int t = dir ? (Tb - 1 - u) : u;
                    const float* row = lpb + (size_t)t * V_;
                    v[r][0] = row[0];
                    #pragma unroll
                    for (int c = 0; c < 5; ++c) v[r][c + 1] = row[labE[c]];
                }
            }
            // ring-slot reuse gate: slot shared with block m-8
            while (__hip_atomic_load(consp, __ATOMIC_RELAXED, WG_SCOPE) < 4 * m - 28)
                __builtin_amdgcn_s_sleep(1);
            #pragma unroll
            for (int r = 0; r < 4; ++r) {
                if (r < n) {
                    const int u = 4 * m + 1 + r;
                    float e[6];
                    e[0] = __builtin_exp2f(v[r][0] * INV_LN2);
                    #pragma unroll
                    for (int c = 0; c < 5; ++c)
                        e[c + 1] = vmask[c] * __builtin_exp2f(v[r][c + 1] * INV_LN2);
                    float* rb = ring + ((u - 1) & (GRING - 1)) * ROWF;
                    ((float2*)rb)[lane]         = make_float2(e[0], e[1]);
                    ((float2*)(rb + 128))[lane] = make_float2(e[2], e[3]);
                    ((float2*)(rb + 256))[lane] = make_float2(e[4], e[5]);
                }
            }
            if (lane == 0)
                __hip_atomic_store(&tags[m & 7], m, __ATOMIC_RELEASE, WG_SCOPE);
        }
    } else if (wid == 0) {
        // ======================= forward consumer =======================
        float skipf[5];
        #pragma unroll
        for (int c = 0; c < 5; ++c) {
            const int j = 5 * lane + c;
            skipf[c] = (j >= 1 && j < L && tg[j] != tg[j - 1]) ? 1.0f : 0.0f;
        }
        float a[10];
        #pragma unroll
        for (int k = 0; k < 10; ++k) a[k] = 0.0f;
        {
            const float p00 = __builtin_exp2f(lpb[0] * INV_LN2);
            const float p01 = __builtin_exp2f(lpb[tg[0]] * INV_LN2);
            if (lane == 0) { a[0] = p00; a[1] = p01; }
        }
        float u9n = 0.0f;                 // inflow alpha_prev[s-1] for s=10*lane
        int K = 0;

        float2 S[4][12];                  // [set][row*3+plane], all const-indexed
        auto readBlock = [&](int set, int m) {
            const int base = ((4 * m) & (GRING - 1)) * ROWF + 2 * lane;
            #pragma unroll
            for (int r = 0; r < 4; ++r)
                #pragma unroll
                for (int pl = 0; pl < 3; ++pl)
                    S[set][r * 3 + pl] =
                        *(const float2*)&ringF[base + r * ROWF + pl * 128];
        };
        auto rowCore = [&](float2 c0, float2 c1, float2 c2) {
            const float u9 = u9n;
            const float p0 = c0.x;
            a[9] = (a[9] + a[8] + skipf[4] * a[7]) * c2.y;
            const float t9 = __shfl_up(a[9], 1, 64);   // early-produce
            u9n = (lane == 0) ? 0.0f : t9;
            a[8] = (a[8] + a[7]) * p0;
            a[7] = (a[7] + a[6] + skipf[3] * a[5]) * c2.x;
            a[6] = (a[6] + a[5]) * p0;
            a[5] = (a[5] + a[4] + skipf[2] * a[3]) * c1.y;
            a[4] = (a[4] + a[3]) * p0;
            a[3] = (a[3] + a[2] + skipf[1] * a[1]) * c1.x;
            a[2] = (a[2] + a[1]) * p0;
            a[1] = (a[1] + a[0] + skipf[0] * u9) * c0.y;   // late-consume
            a[0] = (a[0] + u9) * p0;
        };
        auto row4 = [&](int set) {
            #pragma unroll
            for (int r = 0; r < 4; ++r)
                rowCore(S[set][r * 3], S[set][r * 3 + 1], S[set][r * 3 + 2]);
        };
        auto body = [&](int m, int setc, int setp) {
            if (4 * (m + 2) + 1 <= Uf) {
                poll_eq(&tagF[(m + 2) & 7], m + 2);
                readBlock(setp, m + 2);
            }
            row4(setc);
            if (lane == 0)
                __hip_atomic_store(&consF, 4 * m + 4, __ATOMIC_RELAXED, WG_SCOPE);
        };

        const int MB4 = (Uf / 4) & ~3;
        poll_eq(&tagF[0], 0); readBlock(0, 0);
        poll_eq(&tagF[1], 1); readBlock(1, 1);
        for (int mb = 0; mb < MB4; mb += 4) {
            body(mb + 0, 0, 2);
            body(mb + 1, 1, 3);
            { const int ks = wave_rescale(a, K); u9n = ldexpf(u9n, ks); }  // 8 rows
            body(mb + 2, 2, 0);
            body(mb + 3, 3, 1);
            { const int ks = wave_rescale(a, K); u9n = ldexpf(u9n, ks); }  // 8 rows
        }
        // tail: blocks MB4 (set0), MB4+1 (set1) partially, then direct ring rows
        #pragma unroll
        for (int r = 0; r < 4; ++r)
            if (4 * MB4 + 1 + r <= Uf)
                rowCore(S[0][r * 3], S[0][r * 3 + 1], S[0][r * 3 + 2]);
        #pragma unroll
        for (int r = 0; r < 4; ++r)
            if (4 * MB4 + 5 + r <= Uf)
                rowCore(S[1][r * 3], S[1][r * 3 + 1], S[1][r * 3 + 2]);
        { const int ks = wave_rescale(a, K); u9n = ldexpf(u9n, ks); }      // <=8 rows
        for (int u = 4 * MB4 + 9; u <= Uf; ++u) {                          // <=7 rows
            const int bu = (u - 1) >> 2;
            poll_eq(&tagF[bu & 7], bu);
            const int base = ((u - 1) & (GRING - 1)) * ROWF + 2 * lane;
            const float2 c0 = *(const float2*)&ringF[base];
            const float2 c1 = *(const float2*)&ringF[base + 128];
            const float2 c2 = *(const float2*)&ringF[base + 256];
            rowCore(c0, c1, c2);
        }

        #pragma unroll
        for (int k = 0; k < 10; ++k) dumpA[10 * lane + k] = a[k];
        if (lane == 0) {
            KFsh = K;
            __hip_atomic_store(&consF, Uf + 64, __ATOMIC_RELAXED, WG_SCOPE);
        }
    } else {
        // ======================= backward consumer =======================
        float sB[5];                  // skip into s+2 (odd): label j = 5*lane+c+1
        #pragma unroll
        for (int c = 0; c < 5; ++c) {
            const int j = 5 * lane + c + 1;
            sB[c] = (j < L && tg[j] != tg[j - 1]) ? 1.0f : 0.0f;
        }
        float g[10];
        #pragma unroll
        for (int k = 0; k < 10; ++k) g[k] = 0.0f;
        {   // g_{Tb-1}: nonzero at s=2L (blank) and s=2L-1 (last label)
            const float pb = __builtin_exp2f(lpb[(size_t)(Tb - 1) * V_] * INV_LN2);
            const float pl = __builtin_exp2f(lpb[(size_t)(Tb - 1) * V_ + tg[L - 1]] * INV_LN2);
            #pragma unroll
            for (int k = 0; k < 10; ++k) {
                const int s = 10 * lane + k;
                if (s == 2 * L)     g[k] = pb;
                if (s == 2 * L - 1) g[k] = pl;
            }
        }
        float t0 = __shfl_down(g[0], 1, 64), t1 = __shfl_down(g[1], 1, 64);
        float d0n = (lane == 63) ? 0.0f : t0;
        float d1n = (lane == 63) ? 0.0f : t1;
        int K = 0;

        float2 S[4][12];
        auto readBlock = [&](int set, int m) {
            const int base = ((4 * m) & (GRING - 1)) * ROWF + 2 * lane;
            #pragma unroll
            for (int r = 0; r < 4; ++r)
                #pragma unroll
                for (int pl = 0; pl < 3; ++pl)
                    S[set][r * 3 + pl] =
                        *(const float2*)&ringB[base + r * ROWF + pl * 128];
        };
        auto rowCore = [&](float2 c0, float2 c1, float2 c2) {
            const float d0 = d0n, d1 = d1n;
            const float p0 = c0.x;
            g[0] = (g[0] + g[1]) * p0;
            g[1] = (g[1] + g[2] + sB[0] * g[3]) * c0.y;
            const float q0 = __shfl_down(g[0], 1, 64);   // early-produce
            const float q1 = __shfl_down(g[1], 1, 64);
            d0n = (lane == 63) ? 0.0f : q0;
            d1n = (lane == 63) ? 0.0f : q1;
            g[2] = (g[2] + g[3]) * p0;
            g[3] = (g[3] + g[4] + sB[1] * g[5]) * c1.x;
            g[4] = (g[4] + g[5]) * p0;
            g[5] = (g[5] + g[6] + sB[2] * g[7]) * c1.y;
            g[6] = (g[6] + g[7]) * p0;
            g[7] = (g[7] + g[8] + sB[3] * g[9]) * c2.x;
            g[8] = (g[8] + g[9]) * p0;
            g[9] = (g[9] + d0 + sB[4] * d1) * c2.y;      // late-consume
        };
        auto row4 = [&](int set) {
            #pragma unroll
            for (int r = 0; r < 4; ++r)
                rowCore(S[set][r * 3], S[set][r * 3 + 1], S[set][r * 3 + 2]);
        };
        auto body = [&](int m, int setc, int setp) {
            if (4 * (m + 2) + 1 <= Ub) {
                poll_eq(&tagB[(m + 2) & 7], m + 2);
                readBlock(setp, m + 2);
            }
            row4(setc);
            if (lane == 0)
                __hip_atomic_store(&consB, 4 * m + 4, __ATOMIC_RELAXED, WG_SCOPE);
        };

        const int MB4 = (Ub / 4) & ~3;
        poll_eq(&tagB[0], 0); readBlock(0, 0);
        poll_eq(&tagB[1], 1); readBlock(1, 1);
        for (int mb = 0; mb < MB4; mb += 4) {
            body(mb + 0, 0, 2);
            body(mb + 1, 1, 3);
            { const int ks = wave_rescale(g, K);
              d0n = ldexpf(d0n, ks); d1n = ldexpf(d1n, ks); }
            body(mb + 2, 2, 0);
            body(mb + 3, 3, 1);
            { const int ks = wave_rescale(g, K);
              d0n = ldexpf(d0n, ks); d1n = ldexpf(d1n, ks); }
        }
        #pragma unroll
        for (int r = 0; r < 4; ++r)
            if (4 * MB4 + 1 + r <= Ub)
                rowCore(S[0][r * 3], S[0][r * 3 + 1], S[0][r * 3 + 2]);
        #pragma unroll
        for (int r = 0; r < 4; ++r)
            if (4 * MB4 + 5 + r <= Ub)
                rowCore(S[1][r * 3], S[1][r * 3 + 1], S[1][r * 3 + 2]);
        { const int ks = wave_rescale(g, K);
          d0n = ldexpf(d0n, ks); d1n = ldexpf(d1n, ks); }
        for (int u = 4 * MB4 + 9; u <= Ub; ++u) {
            const int bu = (u - 1) >> 2;
            poll_eq(&tagB[bu & 7], bu);
            const int base = ((u - 1) & (GRING - 1)) * ROWF + 2 * lane;
            const float2 c0 = *(const float2*)&ringB[base];
            const float2 c1 = *(const float2*)&ringB[base + 128];
            const float2 c2 = *(const float2*)&ringB[base + 256];
            rowCore(c0, c1, c2);
        }

        {   // combine: gext[s] = g[s] + g[s+1] + skip[s+2]*g[s+2] (ascending)
            const float d0 = d0n, d1 = d1n;
            g[0] = g[0] + g[1];
            g[1] = g[1] + g[2] + sB[0] * g[3];
            g[2] = g[2] + g[3];
            g[3] = g[3] + g[4] + sB[1] * g[5];
            g[4] = g[4] + g[5];
            g[5] = g[5] + g[6] + sB[2] * g[7];
            g[6] = g[6] + g[7];
            g[7] = g[7] + g[8] + sB[3] * g[9];
            g[8] = g[8] + g[9];
            g[9] = g[9] + d0 + sB[4] * d1;
        }
        #pragma unroll
        for (int k = 0; k < 10; ++k) dumpB[10 * lane + k] = g[k];
        if (lane == 0) {
            KBsh = K;
            __hip_atomic_store(&consB, Ub + 64, __ATOMIC_RELAXED, WG_SCOPE);
        }
    }

    __syncthreads();
    if (wid == 0) {
        // join in DOUBLE (factors span ~240 bits in f32 frames — R7 lesson)
        double sum = 0.0;
        #pragma unroll
        for (int k = 0; k < 10; ++k)
            sum += (double)dumpA[10 * lane + k] * (double)dumpB[10 * lane + k];
        #pragma unroll
        for (int d = 1; d < 64; d <<= 1) sum += __shfl_xor(sum, d, 64);
        if (lane == 0) {
            float loss = 0.0f;                     // infeasible (sum<=0) -> 0
            if (sum > 0.0) {
                const long long ub = __double_as_longlong(sum);
                const int ex = (int)((ub >> 52) & 2047) - 1023;
                const double f = __longlong_as_double(
                    (ub & 0x000FFFFFFFFFFFFFLL) | 0x3FF0000000000000LL);
                const float ll2 = __builtin_log2f((float)f)
                                + (float)(ex - KFsh - KBsh);
                loss = -(ll2 * LN2);
                if (!(loss <= 1e29f)) loss = 0.0f; // zero_infinity
            }
            ws[b] = loss / (float)L;
        }
    }
}

__global__ void ctc_reduce_kernel(const float* __restrict__ ws, float* __restrict__ out) {
    float v = ws[threadIdx.x];
    #pragma unroll
    for (int o = 32; o > 0; o >>= 1) v += __shfl_down(v, o);
    if (threadIdx.x == 0) out[0] = v / (float)B_;
}

extern "C" void kernel_launch(void* const* d_in, const int* in_sizes, int n_in,
                              void* d_out, int out_size, void* d_ws, size_t ws_size,
                              hipStream_t stream) {
    const float* lp      = (const float*)d_in[0];
    const int*   in_len  = (const int*)d_in[1];
    const int*   tgt     = (const int*)d_in[2];
    const int*   tgt_len = (const int*)d_in[3];
    float* loss = (float*)d_ws;
    float* out  = (float*)d_out;

    ctc_fused6<<<B_, 768, 0, stream>>>(lp, in_len, tgt, tgt_len, loss);
    ctc_reduce_kernel<<<1, 64, 0, stream>>>(loss, out);
}